// Round 5
// baseline (277.455 us; speedup 1.0000x reference)
//
#include <hip/hip_runtime.h>
#include <hip/hip_bf16.h>

#define N_PTS 12288
#define DIM   64
#define KSEL  16
#define CAPB  10    // per-lane-per-list LDS candidate buffer depth
#define XTR   24    // per-(row,chunk) survivors handed to the merge kernel

typedef __bf16 bf16x8 __attribute__((ext_vector_type(8)));
typedef float  f32x4  __attribute__((ext_vector_type(4)));

// ---------------------------------------------------------------------------
// Kernel A: S1 = sum(sq), Sx[d] = column sums (closed-form sigma2), bf16 copy
// of coords, and the norm-augmentation rows:
//   exta8[j] = [h_j, l_j, 1, 1, 0..]   (A-role, K-ext dims 0..7)
//   extb8[i] = [-.5, -.5, -.5h_i, -.5l_i, 0..] (B-role)
// so that ext-MFMA contributes -(sq_i+sq_j)/2 and acc = -d2/2 (+eps shift
// dropped: constant, order-preserving). h+l = fp32 sq to ~2e-3.
// ---------------------------------------------------------------------------
__global__ __launch_bounds__(256) void stats_kernel(
    const float* __restrict__ coords,
    float* __restrict__ s1,
    float* __restrict__ sx,
    __bf16* __restrict__ chi,
    __bf16* __restrict__ exta8,
    __bf16* __restrict__ extb8)
{
    __shared__ float colsh[4][64];
    const int lane = threadIdx.x & 63;
    const int wave = threadIdx.x >> 6;
    const int gw   = blockIdx.x * 4 + wave;     // 0..1023
    float colsum = 0.f, sqsum = 0.f;
    for (int r = gw; r < N_PTS; r += 1024) {
        const float x = coords[r * DIM + lane];
        chi[r * DIM + lane] = (__bf16)x;
        colsum += x;
        float p = x * x;
        #pragma unroll
        for (int off = 32; off > 0; off >>= 1)
            p += __shfl_xor(p, off, 64);
        if (lane == 0) {
            sqsum += p;
            const __bf16 h  = (__bf16)p;
            const float  hf = (float)h;
            const __bf16 lo = (__bf16)(p - hf);
            bf16x8 ea, eb;
            #pragma unroll
            for (int t = 0; t < 8; ++t) { ea[t] = (__bf16)0.0f; eb[t] = (__bf16)0.0f; }
            ea[0] = h; ea[1] = lo; ea[2] = (__bf16)1.0f; ea[3] = (__bf16)1.0f;
            eb[0] = (__bf16)-0.5f; eb[1] = (__bf16)-0.5f;
            eb[2] = (__bf16)(-0.5f * hf); eb[3] = (__bf16)(-0.5f * (float)lo);
            ((bf16x8*)exta8)[r] = ea;
            ((bf16x8*)extb8)[r] = eb;
        }
    }
    colsh[wave][lane] = colsum;
    __syncthreads();
    if (wave == 0) {
        const float c = colsh[0][lane] + colsh[1][lane]
                      + colsh[2][lane] + colsh[3][lane];
        atomicAdd(&sx[lane], c);
    }
    if (lane == 0) atomicAdd(s1, sqsum);
}

// Branchless insert of packed key c into a descending-sorted 8-list
// (v[0] = max = screen threshold). Caller guarantees c < v[0].
__device__ __forceinline__ void insert8(unsigned (&v)[8], unsigned c)
{
    #pragma unroll
    for (int t = 0; t < 7; ++t) {
        const bool shift = (v[t + 1] > c);
        const bool place = (!shift) && (v[t] > c);
        v[t] = shift ? v[t + 1] : (place ? c : v[t]);
    }
    if (v[7] > c) v[7] = c;
}

__device__ __forceinline__ void drain(const unsigned* buf, int cnt,
                                      unsigned (&v)[8], int tid)
{
    #pragma unroll 1
    for (int p = 0; p < CAPB; ++p) {
        if (p < cnt) {
            const unsigned c = buf[p * 256 + tid];
            if (c < v[0]) insert8(v, c);
        }
    }
}

// ---------------------------------------------------------------------------
// Kernel B (scan): augmented bf16-MFMA gives acc = -d2/2 (all negative, so
// raw float bits ascend with d2). Key = (bits & 0xFFFFC000) | j. Per-lane
// top-8 with pooled-quad row threshold; per-(row,chunk) top-24 to global ws.
// Block = 256 thr / 4 waves, 32 i-rows; wave scans 1/4 of the j-chunk.
// ---------------------------------------------------------------------------
template<int CHUNKS>
__global__ __launch_bounds__(256) void scan_kernel(
    const __bf16* __restrict__ chi,
    const __bf16* __restrict__ exta8,
    const __bf16* __restrict__ extb8,
    unsigned* __restrict__ wsknn)            // [N][CHUNKS][XTR]
{
    // scan buffers (2*CAPB*256 = 5120 u32) alias merge rows (32*132 = 4224)
    __shared__ __align__(16) unsigned smem[5120];

    const int tid  = threadIdx.x;
    const int lane = tid & 63;
    const int wave = tid >> 6;
    const int col  = lane & 15;
    const int quad = lane >> 4;
    const int ibase = (int)blockIdx.x * 32;
    const int i0 = ibase + col;
    const int i1 = ibase + 16 + col;

    const bf16x8* cp = (const bf16x8*)chi;
    const bf16x8 b00 = cp[i0 * 8 + quad], b01 = cp[i0 * 8 + quad + 4];
    const bf16x8 b10 = cp[i1 * 8 + quad], b11 = cp[i1 * 8 + quad + 4];
    bf16x8 bx0 = ((const bf16x8*)extb8)[i0];
    bf16x8 bx1 = ((const bf16x8*)extb8)[i1];
    if (quad != 0) {                       // ext dims live in K 0..7 only
        #pragma unroll
        for (int t = 0; t < 8; ++t) { bx0[t] = (__bf16)0.0f; bx1[t] = (__bf16)0.0f; }
    }

    unsigned v0[8], v1[8];
    #pragma unroll
    for (int t = 0; t < 8; ++t) { v0[t] = 0xFFFFFFFFu; v1[t] = 0xFFFFFFFFu; }

    unsigned* buf0 = smem;
    unsigned* buf1 = smem + CAPB * 256;
    int c0 = 0, c1 = 0;

    const int chunk = (int)blockIdx.y;
    const int jw = chunk * (N_PTS / CHUNKS) + wave * (N_PTS / CHUNKS / 4);
    const int STEPS = N_PTS / CHUNKS / 64;

    #pragma unroll 1
    for (int s = 0; s < STEPS; ++s) {
        const int j0 = jw + s * 16;
        const int arow = j0 + col;
        const bf16x8 a0 = cp[arow * 8 + quad];
        const bf16x8 a1 = cp[arow * 8 + quad + 4];
        bf16x8 ax = ((const bf16x8*)exta8)[arow];
        if (quad != 0) {
            #pragma unroll
            for (int t = 0; t < 8; ++t) ax[t] = (__bf16)0.0f;
        }
        f32x4 acc0 = {0.f, 0.f, 0.f, 0.f};
        acc0 = __builtin_amdgcn_mfma_f32_16x16x32_bf16(a0, b00, acc0, 0, 0, 0);
        acc0 = __builtin_amdgcn_mfma_f32_16x16x32_bf16(a1, b01, acc0, 0, 0, 0);
        acc0 = __builtin_amdgcn_mfma_f32_16x16x32_bf16(ax, bx0, acc0, 0, 0, 0);
        f32x4 acc1 = {0.f, 0.f, 0.f, 0.f};
        acc1 = __builtin_amdgcn_mfma_f32_16x16x32_bf16(a0, b10, acc1, 0, 0, 0);
        acc1 = __builtin_amdgcn_mfma_f32_16x16x32_bf16(a1, b11, acc1, 0, 0, 0);
        acc1 = __builtin_amdgcn_mfma_f32_16x16x32_bf16(ax, bx1, acc1, 0, 0, 0);

        // pooled threshold: max over quads of v[4] (each quad's 4th-smallest)
        // upper-bounds the row 16th smallest; fold with own v[0].
        unsigned T0 = v0[4], T1 = v1[4];
        { unsigned t = __shfl_xor(T0, 16, 64); T0 = T0 > t ? T0 : t;
          t = __shfl_xor(T0, 32, 64); T0 = T0 > t ? T0 : t; }
        { unsigned t = __shfl_xor(T1, 16, 64); T1 = T1 > t ? T1 : t;
          t = __shfl_xor(T1, 32, 64); T1 = T1 > t ? T1 : t; }
        const unsigned U0 = T0 < v0[0] ? T0 : v0[0];
        const unsigned U1 = T1 < v1[0] ? T1 : v1[0];

        const int jq = j0 + quad * 4;
        #pragma unroll
        for (int r = 0; r < 4; ++r) {
            const int j = jq + r;
            const unsigned pa = (__float_as_uint(acc0[r]) & 0xFFFFC000u) | (unsigned)j;
            const unsigned pb = (__float_as_uint(acc1[r]) & 0xFFFFC000u) | (unsigned)j;
            if (pa < U0) { buf0[c0 * 256 + tid] = pa; ++c0; }
            if (pb < U1) { buf1[c1 * 256 + tid] = pb; ++c1; }
        }
        const int cmax = (c0 > c1) ? c0 : c1;
        if (__any(cmax >= CAPB - 4)) {
            drain(buf0, c0, v0, tid);
            drain(buf1, c1, v1, tid);
            c0 = 0; c1 = 0;
        }
    }
    drain(buf0, c0, v0, tid);
    drain(buf1, c1, v1, tid);

    __syncthreads();                 // scan buffers dead; alias as merge rows
    unsigned* mrow = smem;           // [32][132] (pad to 132: 16B-aligned rows)
    const int slot = wave * 4 + quad;
    #pragma unroll
    for (int t = 0; t < 8; ++t) {
        mrow[col * 132 + slot * 8 + t]        = v0[t];
        mrow[(16 + col) * 132 + slot * 8 + t] = v1[t];
    }
    __syncthreads();

    // Extract the 24 smallest of each row's 128 survivors.
    // Two rows at a time: half-wave per row, 4 reg values/lane, 5-level min.
    const int hl = lane & 31;
    const int hh = lane >> 5;
    #pragma unroll 1
    for (int it = 0; it < 4; ++it) {
        const int row = wave * 8 + it * 2 + hh;
        unsigned lv[4];
        #pragma unroll
        for (int t = 0; t < 4; ++t) lv[t] = mrow[row * 132 + hl * 4 + t];
        #pragma unroll 1
        for (int k = 0; k < XTR; ++k) {
            unsigned m01 = lv[0] < lv[1] ? lv[0] : lv[1];
            unsigned m23 = lv[2] < lv[3] ? lv[2] : lv[3];
            unsigned m = m01 < m23 ? m01 : m23;
            #pragma unroll
            for (int off = 1; off < 32; off <<= 1) {
                const unsigned o = __shfl_xor(m, off, 64);
                m = o < m ? o : m;
            }
            if (hl == k)
                wsknn[((ibase + row) * CHUNKS + chunk) * XTR + k] = m;
            #pragma unroll
            for (int t = 0; t < 4; ++t) if (lv[t] == m) lv[t] = 0xFFFFFFFFu;
        }
    }
}

// ---------------------------------------------------------------------------
// Kernel C (merge): pool CHUNKS*24 survivors/row, top-32 by screen key,
// fp64-exact refine + rank-16 + fp64 laplacian, fp32 out. Self (j==row) is
// in the pool by construction; excluded here via d2=+inf.
// Block 256 thr = 8 half-waves = 8 rows; grid N/8.
// ---------------------------------------------------------------------------
template<int CHUNKS>
__global__ __launch_bounds__(256) void merge_kernel(
    const float* __restrict__ coords,
    const float* __restrict__ pot,
    const float* __restrict__ s1,
    const float* __restrict__ sx,
    const unsigned* __restrict__ wsknn,
    float* __restrict__ out)
{
    constexpr int POOL = CHUNKS * XTR;
    constexpr int NF   = 32;
    __shared__ double   s_inv_den;
    __shared__ unsigned allv[8][POOL];
    __shared__ int      finj[8][NF];
    __shared__ double   refd[8][NF];

    const int tid = threadIdx.x;
    const int hw  = tid >> 5;          // half-wave id = local row
    const int l   = tid & 31;
    const int row = (int)blockIdx.x * 8 + hw;

    if (tid == 0) {
        // sigma2 = mean(dist2 incl. +eps everywhere and +1e6 on the diagonal)
        double S1 = (double)s1[0], m2 = 0.0;
        for (int d = 0; d < DIM; ++d) { double t = (double)sx[d]; m2 += t * t; }
        const double NN = (double)N_PTS;
        s_inv_den = 1.0 / ((2.0 * NN * S1 - 2.0 * m2) / (NN * NN)
                           + 1e-5 + 1e6 / NN + 1e-5);
    }
    for (int t = l; t < POOL; t += 32)
        allv[hw][t] = wsknn[row * POOL + t];
    __syncthreads();

    // rank-select the NF smallest (keys unique -> rank is a bijection)
    for (int t = l; t < POOL; t += 32) {
        const unsigned c = allv[hw][t];
        int rank = 0;
        #pragma unroll 4
        for (int m = 0; m < POOL; ++m) rank += (allv[hw][m] < c) ? 1 : 0;
        if (rank < NF) finj[hw][rank] = (int)(c & 0x3FFFu);
    }
    __syncthreads();

    // fp64 refine (dot + both norms in one pass) + rank-16 + laplacian
    const double inv_den = s_inv_den;
    const int j = finj[hw][l];
    const float4* xi = (const float4*)(coords + row * DIM);
    const float4* xj = (const float4*)(coords + j * DIM);
    double dot = 0.0, sqi = 0.0, sqj = 0.0;
    #pragma unroll
    for (int q = 0; q < DIM / 4; ++q) {
        const float4 a = xi[q], b = xj[q];
        dot += (double)a.x * (double)b.x + (double)a.y * (double)b.y
             + (double)a.z * (double)b.z + (double)a.w * (double)b.w;
        sqi += (double)a.x * (double)a.x + (double)a.y * (double)a.y
             + (double)a.z * (double)a.z + (double)a.w * (double)a.w;
        sqj += (double)b.x * (double)b.x + (double)b.y * (double)b.y
             + (double)b.z * (double)b.z + (double)b.w * (double)b.w;
    }
    double d2 = sqi + sqj + 1e-5 - 2.0 * dot;
    if (j == row) d2 = 1e300;          // self-pair: excluded
    refd[hw][l] = d2;
    __syncthreads();

    int rank = 0;
    #pragma unroll 1
    for (int m = 0; m < NF; ++m) {
        const double o = refd[hw][m];
        rank += (o < d2 || (o == d2 && m < l)) ? 1 : 0;
    }
    const double w = exp(-d2 * inv_den);
    double contrib = (rank < KSEL)
                   ? w * ((double)pot[j] - (double)pot[row]) : 0.0;
    #pragma unroll
    for (int off = 1; off < 32; off <<= 1)
        contrib += __shfl_xor(contrib, off, 64);
    if (l == 0) out[row] = (float)contrib;
}

extern "C" void kernel_launch(void* const* d_in, const int* in_sizes, int n_in,
                              void* d_out, int out_size, void* d_ws, size_t ws_size,
                              hipStream_t stream)
{
    (void)in_sizes; (void)n_in; (void)out_size;
    const float* coords = (const float*)d_in[0];
    const float* pot    = (const float*)d_in[1];
    // d_in[2] is k (always 16, compiled in as KSEL)

    char* w = (char*)d_ws;
    float*  s1    = (float*)w;                         // [1]
    float*  sx    = (float*)(w + 4);                   // [DIM]
    __bf16* chi   = (__bf16*)(w + 512);                // [N][64]   1.57 MB
    __bf16* exta8 = (__bf16*)(w + 512 + 1572864);      // [N][8]    196 KB
    __bf16* extb8 = (__bf16*)(w + 512 + 1572864 + 196608);
    unsigned* wsknn = (unsigned*)(w + 512 + 1572864 + 2 * 196608);

    const size_t base  = 512 + 1572864 + 2 * 196608;   // 1,966,592
    const size_t need6 = base + (size_t)N_PTS * 6 * XTR * 4;  // 9.05 MB
    const size_t need4 = base + (size_t)N_PTS * 4 * XTR * 4;  // 6.69 MB

    hipMemsetAsync((void*)s1, 0, (1 + DIM) * sizeof(float), stream);
    stats_kernel<<<dim3(256), dim3(256), 0, stream>>>(
        coords, s1, sx, chi, exta8, extb8);

    if (ws_size >= need6) {
        scan_kernel<6><<<dim3(N_PTS / 32, 6), dim3(256), 0, stream>>>(
            chi, exta8, extb8, wsknn);
        merge_kernel<6><<<dim3(N_PTS / 8), dim3(256), 0, stream>>>(
            coords, pot, s1, sx, wsknn, (float*)d_out);
    } else if (ws_size >= need4) {
        scan_kernel<4><<<dim3(N_PTS / 32, 4), dim3(256), 0, stream>>>(
            chi, exta8, extb8, wsknn);
        merge_kernel<4><<<dim3(N_PTS / 8), dim3(256), 0, stream>>>(
            coords, pot, s1, sx, wsknn, (float*)d_out);
    } else {
        scan_kernel<2><<<dim3(N_PTS / 32, 2), dim3(256), 0, stream>>>(
            chi, exta8, extb8, wsknn);
        merge_kernel<2><<<dim3(N_PTS / 8), dim3(256), 0, stream>>>(
            coords, pot, s1, sx, wsknn, (float*)d_out);
    }
}